// Round 6
// baseline (434.362 us; speedup 1.0000x reference)
//
#include <hip/hip_runtime.h>
#include <cstdint>
#include <cstddef>

typedef __attribute__((ext_vector_type(8))) __bf16 bf16x8;
typedef __attribute__((ext_vector_type(16))) float floatx16;

struct SrcPtrs { const float* p[9]; };

// ---------------- weight workspace layout (bf16 elems) ----------------
// Frag-major per layer: frag f = t*S + s (t = 32-feature tile, s = 16-k step).
// Each frag = 1024 B = 64 lanes x 16 B; lane l = q2*32 + l31 holds
// row (32t + l31), k = 16s + 8*q2 + {0..7} — exactly the 32x32x16 bf16
// A-operand layout, so one coalesced global_load_dwordx4 per lane feeds the
// MFMA directly from VGPRs. No LDS, no barriers in the main kernel.
// m  mat    K    Nout  S   NT  off(shorts)  remap
// 0  Wd1_0  60   128   4   4   0
// 1  Wd1_1  128  128   8   4   8192
// 2  Wd1_2  128  128   8   4   24576
// 3  Wd2_0  188  128   12  4   40960    k<60 -> 128+k, k>=60 -> k-60
// 4  Wd2_1  128  128   8   4   65536
// 5  Wd2_2  128  128   8   4   81920
// 6  Wd2_3  128  129   8   5   98304    col0 -> row128 (blend), col j+1 -> row j
// 7  Wc_0   152  128   10  4   118784   k<24 -> 128+k, k>=24 -> k-24
// 8  Wc_1   128  3     8   1   139264   rows 3..31 zero
// total 143360 shorts = 286720 B

__global__ void prep_zero(unsigned short* __restrict__ ws) {
  uint4* p = (uint4*)ws;
  const int n = 143360 / 8;
  for (int i = blockIdx.x * blockDim.x + threadIdx.x; i < n; i += gridDim.x * blockDim.x)
    p[i] = make_uint4(0u, 0u, 0u, 0u);
}

__global__ void prep_fill(SrcPtrs sp, unsigned short* __restrict__ ws) {
  const int m  = blockIdx.x >> 4;
  const int sl = blockIdx.x & 15;
  const int K[9]  = {60, 128, 128, 188, 128, 128, 128, 152, 128};
  const int N[9]  = {128, 128, 128, 128, 128, 128, 129, 128, 3};
  const int SS[9] = {4, 8, 8, 12, 8, 8, 8, 10, 8};
  const unsigned OFF[9] = {0u, 8192u, 24576u, 40960u, 65536u, 81920u, 98304u, 118784u, 139264u};
  const int Km = K[m], Nm = N[m], Sm = SS[m];
  const float* __restrict__ src = sp.p[m];
  unsigned short* __restrict__ dst = ws + OFF[m];
  const int tot = Km * Nm;
  for (int i = sl * 256 + (int)threadIdx.x; i < tot; i += 16 * 256) {
    int k = i / Nm;
    int n = i - k * Nm;
    int kk = k, row = n;
    if (m == 3) kk = (k < 60) ? 128 + k : k - 60;
    if (m == 7) kk = (k < 24) ? 128 + k : k - 24;
    if (m == 6) row = (n == 0) ? 128 : n - 1;
    const int t = row >> 5, l31 = row & 31;
    const int s = kk >> 4, q2 = (kk >> 3) & 1, j = kk & 7;
    dst[(t * Sm + s) * 512 + (q2 * 32 + l31) * 8 + j] =
        __builtin_bit_cast(unsigned short, (__bf16)src[i]);
  }
}

// ---------------- main fused kernel ----------------

#if defined(__has_builtin)
#if __has_builtin(__builtin_amdgcn_permlane32_swap)
#define HAVE_PLSWAP 1
#endif
#endif
#ifndef HAVE_PLSWAP
#define HAVE_PLSWAP 0
#endif

__device__ __forceinline__ unsigned pk2(float a, float b) {
  unsigned short ua = __builtin_bit_cast(unsigned short, (__bf16)a);
  unsigned short ub = __builtin_bit_cast(unsigned short, (__bf16)b);
  return (unsigned)ua | ((unsigned)ub << 16);
}

// lo = q2==0 ? own a : partner's b ; hi = q2==0 ? partner's a : own b
__device__ __forceinline__ void half_swap(unsigned a, unsigned b, int q2,
                                          unsigned& lo, unsigned& hi) {
#if HAVE_PLSWAP
  auto r = __builtin_amdgcn_permlane32_swap(a, b, false, false);
  lo = r[0]; hi = r[1];
#else
  unsigned sa = __shfl_xor(a, 32, 64);
  unsigned sb = __shfl_xor(b, 32, 64);
  lo = q2 ? sb : a;
  hi = q2 ? b : sa;
#endif
}

// sin/cos of v * pi * 2^f == sin/cos(2*pi*rev), rev = v * 2^(f-1) (HW revolutions)
// KIND 0: positional enc, k2 = 16*sl + 8*q2 + j: d=k2/20, f=(k2%20)>>1, valid k2<60
// KIND 1: view enc: d=3+k2/8, f=(k2%8)>>1, valid k2<24
template <int KIND>
__device__ __forceinline__ bf16x8 trig_frag(const float (&x)[6], int q2, int sl) {
  bf16x8 r;
#pragma unroll
  for (int j = 0; j < 8; ++j) {
    const int kA = 16 * sl + j;       // q2 == 0
    const int kB = 16 * sl + 8 + j;   // q2 == 1
    int dA, dB; float scA, scB; bool vA, vB;
    if (KIND == 0) {
      vA = kA < 60; vB = kB < 60;
      dA = kA / 20; dB = kB / 20;
      scA = (float)(1 << ((kA % 20) >> 1)) * 0.5f;
      scB = (float)(1 << ((kB % 20) >> 1)) * 0.5f;
    } else {
      vA = kA < 24; vB = kB < 24;
      dA = 3 + (kA >> 3); dB = 3 + (kB >> 3);
      scA = (float)(1 << ((kA & 7) >> 1)) * 0.5f;
      scB = (float)(1 << ((kB & 7) >> 1)) * 0.5f;
    }
    float v  = q2 ? x[dB] : x[dA];
    float sc = q2 ? scB : scA;
    bool ok  = q2 ? vB : vA;
    float rev = v * sc;
    float t = (j & 1) ? __builtin_amdgcn_cosf(rev) : __builtin_amdgcn_sinf(rev);
    r[j] = (__bf16)(ok ? t : 0.0f);
  }
  return r;
}

// 32x32x16 bf16 MFMA, A = weights (m=feature) streamed from L2 via coalesced
// dwordx4 loads (frag-major layout), B = activations (n=point) register-resident.
// Wave owns 2 m-tiles (64 points) x ALL n-tiles; no LDS, no __syncthreads.
// pkv[m][j]: feats 8j+4q2+{0..3} of point (base+64w+32m+l31), bf16-packed.
// S: k-steps. SL: k-steps from pkv (rest from tail). NT: 32-feature tiles.
// OUTM: 0=pkv, 1=d2_3 (pkv feats + density/blend), 2=c_1 (rgb).
template <int S, int SL, int NT, bool RELU, int OUTM>
__device__ __forceinline__ void run_layer(const unsigned short* __restrict__ wsrc,
                                          uint2 (&pkv)[2][16],
                                          const bf16x8 (&tail)[2][4],
                                          float* __restrict__ out, int base, int tid) {
  const int lane = tid & 63;
  const int w = tid >> 6;
  const int q2 = lane >> 5;
  const int l31 = lane & 31;
  const int pt0 = base + w * 64 + l31;
  const int pt1 = pt0 + 32;

  // input copy as B-frags (enables in-place pkv update in the epilogue)
  bf16x8 bf[2][SL > 0 ? SL : 1];
#pragma unroll
  for (int s = 0; s < SL; ++s) {
#pragma unroll
    for (int m = 0; m < 2; ++m) {
      uint2 p0 = pkv[m][2 * s], p1 = pkv[m][2 * s + 1];
      unsigned w0, w1, w2, w3;
      half_swap(p0.x, p1.x, q2, w0, w2);
      half_swap(p0.y, p1.y, q2, w1, w3);
      uint4 u = make_uint4(w0, w1, w2, w3);
      bf[m][s] = __builtin_bit_cast(bf16x8, u);
    }
  }

  const uint4* __restrict__ wp = (const uint4*)wsrc;
#pragma unroll
  for (int t = 0; t < NT; ++t) {
    floatx16 acc[2];
#pragma unroll
    for (int i = 0; i < 16; ++i) { acc[0][i] = 0.0f; acc[1][i] = 0.0f; }
#pragma unroll
    for (int s = 0; s < S; ++s) {
      uint4 a4 = wp[(t * S + s) * 64 + lane];
      bf16x8 A = __builtin_bit_cast(bf16x8, a4);
      const int si = (s < SL) ? s : 0;
      const int ti = (s < SL) ? 0 : (s - SL);
      bf16x8 B0 = (s < SL) ? bf[0][si] : tail[0][ti];
      bf16x8 B1 = (s < SL) ? bf[1][si] : tail[1][ti];
      acc[0] = __builtin_amdgcn_mfma_f32_32x32x16_bf16(A, B0, acc[0], 0, 0, 0);
      acc[1] = __builtin_amdgcn_mfma_f32_32x32x16_bf16(A, B1, acc[1], 0, 0, 0);
    }
    if (OUTM == 2) {
      if (q2 == 0) {  // rgb = rows 0..2 -> regs 0..2 at q2==0
        float* o0 = out + (size_t)pt0 * 5;
        o0[0] = acc[0][0]; o0[1] = acc[0][1]; o0[2] = acc[0][2];
        float* o1 = out + (size_t)pt1 * 5;
        o1[0] = acc[1][0]; o1[1] = acc[1][1]; o1[2] = acc[1][2];
      }
    } else {
      if (OUTM == 0 || t < 4) {
#pragma unroll
        for (int m = 0; m < 2; ++m) {
#pragma unroll
          for (int gg = 0; gg < 4; ++gg) {
            float b0 = acc[m][4 * gg], b1 = acc[m][4 * gg + 1];
            float b2 = acc[m][4 * gg + 2], b3 = acc[m][4 * gg + 3];
            if (RELU) {
              b0 = fmaxf(b0, 0.f); b1 = fmaxf(b1, 0.f);
              b2 = fmaxf(b2, 0.f); b3 = fmaxf(b3, 0.f);
            }
            pkv[m][4 * t + gg] = make_uint2(pk2(b0, b1), pk2(b2, b3));
          }
        }
      }
      if (OUTM == 1 && q2 == 0) {
        if (t == 0) {  // density = feature[:,0] = row 0 (f32, pre-rounding)
          out[(size_t)pt0 * 5 + 3] = acc[0][0];
          out[(size_t)pt1 * 5 + 3] = acc[1][0];
        }
        if (t == 4) {  // blending = sigmoid(row 128)
          out[(size_t)pt0 * 5 + 4] = 1.0f / (1.0f + __expf(-acc[0][0]));
          out[(size_t)pt1 * 5 + 4] = 1.0f / (1.0f + __expf(-acc[1][0]));
        }
      }
    }
  }
}

__global__ __launch_bounds__(256, 2) void nerf_main(const float* __restrict__ x,
                                                    const unsigned short* __restrict__ ws,
                                                    float* __restrict__ out) {
  const int tid = (int)threadIdx.x;
  const int base = (int)blockIdx.x * 256;
  const int lane = tid & 63;
  const int w = tid >> 6;
  const int q2 = lane >> 5;
  const int l31 = lane & 31;
  const int pt0 = base + w * 64 + l31;

  // per-lane x in registers (pt fixed per lane for whole kernel)
  float x0[6], x1[6];
  {
    const float* a = x + (size_t)pt0 * 6;
    const float* b = x + (size_t)(pt0 + 32) * 6;
#pragma unroll
    for (int c = 0; c < 3; ++c) {
      float2 u = *(const float2*)(a + 2 * c);
      float2 v = *(const float2*)(b + 2 * c);
      x0[2 * c] = u.x; x0[2 * c + 1] = u.y;
      x1[2 * c] = v.x; x1[2 * c + 1] = v.y;
    }
  }

  // positional trig frags computed ONCE (used by d1_0 and d2_0)
  bf16x8 pkt[2][4];
#pragma unroll
  for (int sl = 0; sl < 4; ++sl) {
    pkt[0][sl] = trig_frag<0>(x0, q2, sl);
    pkt[1][sl] = trig_frag<0>(x1, q2, sl);
  }

  uint2 pkv[2][16];

  //          S   SL NT relu  out
  run_layer< 4, 0, 4, true , 0>(ws + 0u,      pkv, pkt, out, base, tid); // d1_0 (B = enc_pos)
  run_layer< 8, 8, 4, true , 0>(ws + 8192u,   pkv, pkt, out, base, tid); // d1_1
  run_layer< 8, 8, 4, false, 0>(ws + 24576u,  pkv, pkt, out, base, tid); // d1_2 -> part1
  run_layer<12, 8, 4, true , 0>(ws + 40960u,  pkv, pkt, out, base, tid); // d2_0 [part1|enc_pos]
  run_layer< 8, 8, 4, true , 0>(ws + 65536u,  pkv, pkt, out, base, tid); // d2_1
  run_layer< 8, 8, 4, true , 0>(ws + 81920u,  pkv, pkt, out, base, tid); // d2_2
  run_layer< 8, 8, 5, false, 1>(ws + 98304u,  pkv, pkt, out, base, tid); // d2_3 -> feat,dens,blend

  // view trig frags (built only now; pkt regs are dead after d2_0)
  bf16x8 vw[2][4];
#pragma unroll
  for (int sl = 0; sl < 2; ++sl) {
    vw[0][sl] = trig_frag<1>(x0, q2, sl);
    vw[1][sl] = trig_frag<1>(x1, q2, sl);
  }
  vw[0][2] = vw[0][0]; vw[0][3] = vw[0][0];  // unused, keep defined
  vw[1][2] = vw[1][0]; vw[1][3] = vw[1][0];

  run_layer<10, 8, 4, true , 0>(ws + 118784u, pkv, vw,  out, base, tid); // c_0 [feature|enc_view]
  run_layer< 8, 8, 1, false, 2>(ws + 139264u, pkv, pkt, out, base, tid); // c_1 -> rgb
}

extern "C" void kernel_launch(void* const* d_in, const int* in_sizes, int n_in,
                              void* d_out, int out_size, void* d_ws, size_t ws_size,
                              hipStream_t stream) {
  (void)n_in; (void)out_size; (void)ws_size;
  const float* x = (const float*)d_in[0];
  SrcPtrs sp;
  for (int i = 0; i < 9; ++i) sp.p[i] = (const float*)d_in[1 + i];
  unsigned short* ws = (unsigned short*)d_ws;
  float* out = (float*)d_out;
  const int N = in_sizes[0] / 6;

  prep_zero<<<70, 256, 0, stream>>>(ws);
  prep_fill<<<144, 256, 0, stream>>>(sp, ws);
  nerf_main<<<N / 256, 256, 0, stream>>>(x, ws, out);
}

// Round 7
// 360.572 us; speedup vs baseline: 1.2046x; 1.2046x over previous
//
#include <hip/hip_runtime.h>
#include <cstdint>
#include <cstddef>

typedef __attribute__((ext_vector_type(8))) __bf16 bf16x8;
typedef __attribute__((ext_vector_type(16))) float floatx16;

struct SrcPtrs { const float* p[9]; };

// ---------------- weight workspace layout (bf16 elems) ----------------
// Frag-major per layer: frag f = t*S + s (t = 32-feature tile, s = 16-k step).
// Each frag = 1024 B = 64 lanes x 16 B; lane l = q2*32 + l31 holds
// row (32t + l31), k = 16s + 8*q2 + {0..7} — exactly the 32x32x16 bf16
// A-operand layout. Serves BOTH paths: coalesced global_load_dwordx4 from L2
// and (after contiguous staging) conflict-free ds_read_b128 from LDS.
// m  mat    K    Nout  S   NT  off(shorts)  remap
// 0  Wd1_0  60   128   4   4   0
// 1  Wd1_1  128  128   8   4   8192
// 2  Wd1_2  128  128   8   4   24576
// 3  Wd2_0  188  128   12  4   40960    k<60 -> 128+k, k>=60 -> k-60
// 4  Wd2_1  128  128   8   4   65536
// 5  Wd2_2  128  128   8   4   81920
// 6  Wd2_3  128  129   8   5   98304    col0 -> row128 (blend), col j+1 -> row j
// 7  Wc_0   152  128   10  4   118784   k<24 -> 128+k, k>=24 -> k-24
// 8  Wc_1   128  3     8   1   139264   rows 3..31 zero
// total 143360 shorts = 286720 B

__global__ void prep_zero(unsigned short* __restrict__ ws) {
  uint4* p = (uint4*)ws;
  const int n = 143360 / 8;
  for (int i = blockIdx.x * blockDim.x + threadIdx.x; i < n; i += gridDim.x * blockDim.x)
    p[i] = make_uint4(0u, 0u, 0u, 0u);
}

__global__ void prep_fill(SrcPtrs sp, unsigned short* __restrict__ ws) {
  const int m  = blockIdx.x >> 4;
  const int sl = blockIdx.x & 15;
  const int K[9]  = {60, 128, 128, 188, 128, 128, 128, 152, 128};
  const int N[9]  = {128, 128, 128, 128, 128, 128, 129, 128, 3};
  const int SS[9] = {4, 8, 8, 12, 8, 8, 8, 10, 8};
  const unsigned OFF[9] = {0u, 8192u, 24576u, 40960u, 65536u, 81920u, 98304u, 118784u, 139264u};
  const int Km = K[m], Nm = N[m], Sm = SS[m];
  const float* __restrict__ src = sp.p[m];
  unsigned short* __restrict__ dst = ws + OFF[m];
  const int tot = Km * Nm;
  for (int i = sl * 256 + (int)threadIdx.x; i < tot; i += 16 * 256) {
    int k = i / Nm;
    int n = i - k * Nm;
    int kk = k, row = n;
    if (m == 3) kk = (k < 60) ? 128 + k : k - 60;
    if (m == 7) kk = (k < 24) ? 128 + k : k - 24;
    if (m == 6) row = (n == 0) ? 128 : n - 1;
    const int t = row >> 5, l31 = row & 31;
    const int s = kk >> 4, q2 = (kk >> 3) & 1, j = kk & 7;
    dst[(t * Sm + s) * 512 + (q2 * 32 + l31) * 8 + j] =
        __builtin_bit_cast(unsigned short, (__bf16)src[i]);
  }
}

// ---------------- main fused kernel ----------------

#if defined(__has_builtin)
#if __has_builtin(__builtin_amdgcn_permlane32_swap)
#define HAVE_PLSWAP 1
#endif
#endif
#ifndef HAVE_PLSWAP
#define HAVE_PLSWAP 0
#endif

__device__ __forceinline__ unsigned pk2(float a, float b) {
  unsigned short ua = __builtin_bit_cast(unsigned short, (__bf16)a);
  unsigned short ub = __builtin_bit_cast(unsigned short, (__bf16)b);
  return (unsigned)ua | ((unsigned)ub << 16);
}

__device__ __forceinline__ void stage16(const void* g, void* l) {
  __builtin_amdgcn_global_load_lds(
      (const __attribute__((address_space(1))) unsigned int*)g,
      (__attribute__((address_space(3))) unsigned int*)l, 16, 0, 0);
}

// lo = q2==0 ? own a : partner's b ; hi = q2==0 ? partner's a : own b
__device__ __forceinline__ void half_swap(unsigned a, unsigned b, int q2,
                                          unsigned& lo, unsigned& hi) {
#if HAVE_PLSWAP
  auto r = __builtin_amdgcn_permlane32_swap(a, b, false, false);
  lo = r[0]; hi = r[1];
#else
  unsigned sa = __shfl_xor(a, 32, 64);
  unsigned sb = __shfl_xor(b, 32, 64);
  lo = q2 ? sb : a;
  hi = q2 ? b : sa;
#endif
}

// sin/cos of v * pi * 2^f == sin/cos(2*pi*rev), rev = v * 2^(f-1) (HW revolutions)
// KIND 0: positional enc, k2 = 16*sl + 8*q2 + j: d=k2/20, f=(k2%20)>>1, valid k2<60
// KIND 1: view enc: d=3+k2/8, f=(k2%8)>>1, valid k2<24
template <int KIND>
__device__ __forceinline__ bf16x8 trig_frag(const float (&x)[6], int q2, int sl) {
  bf16x8 r;
#pragma unroll
  for (int j = 0; j < 8; ++j) {
    const int kA = 16 * sl + j;       // q2 == 0
    const int kB = 16 * sl + 8 + j;   // q2 == 1
    int dA, dB; float scA, scB; bool vA, vB;
    if (KIND == 0) {
      vA = kA < 60; vB = kB < 60;
      dA = kA / 20; dB = kB / 20;
      scA = (float)(1 << ((kA % 20) >> 1)) * 0.5f;
      scB = (float)(1 << ((kB % 20) >> 1)) * 0.5f;
    } else {
      vA = kA < 24; vB = kB < 24;
      dA = 3 + (kA >> 3); dB = 3 + (kB >> 3);
      scA = (float)(1 << ((kA & 7) >> 1)) * 0.5f;
      scB = (float)(1 << ((kB & 7) >> 1)) * 0.5f;
    }
    float v  = q2 ? x[dB] : x[dA];
    float sc = q2 ? scB : scA;
    bool ok  = q2 ? vB : vA;
    float rev = v * sc;
    float t = (j & 1) ? __builtin_amdgcn_cosf(rev) : __builtin_amdgcn_sinf(rev);
    r[j] = (__bf16)(ok ? t : 0.0f);
  }
  return r;
}

// 32x32x16 bf16 MFMA, A = weights (m=feature), B = activations (n=point),
// register-resident across layers (pkv, half-exchanged via permlane32_swap).
// Wave owns 2 m-tiles (64 points) x ALL n-tiles (A-reuse x2).
// HYBRID A-sourcing: tiles t<HT read A from the LDS ping-pong buffer (staged
// one full layer ahead -> the single __syncthreads per layer never waits on
// fresh vmem); tiles t>=HT stream A straight from L2 (separate pipe).
// pkv[m][j]: feats 8j+4q2+{0..3} of point (base+64w+32m+l31), bf16-packed.
// S: k-steps. SL: k-steps from pkv (rest from tail). NT: 32-feature tiles.
// HT: LDS-sourced tiles. PP: LDS buffer parity. OUTM: 0=pkv, 1=d2_3, 2=c_1.
template <int S, int SL, int NT, int HT, int PP, bool RELU, int OUTM>
__device__ __forceinline__ void run_layer(const unsigned short* __restrict__ wsrc,
                                          const unsigned short* __restrict__ nsrc, int nbytes,
                                          unsigned short* __restrict__ sWt,
                                          uint2 (&pkv)[2][16],
                                          const bf16x8 (&tail)[2][4],
                                          float* __restrict__ out, int base, int tid) {
  const int lane = tid & 63;
  const int w = tid >> 6;
  const int q2 = lane >> 5;
  const int l31 = lane & 31;
  const int pt0 = base + w * 64 + l31;
  const int pt1 = pt0 + 32;

  __syncthreads();  // buf[PP] valid (staged a full layer ago); buf[PP^1] free

  // stage NEXT layer's LDS-half into buf[PP^1] (drains at the NEXT barrier)
  if (nbytes > 0) {
    const uint4* __restrict__ s4 = (const uint4*)nsrc;
    uint4* __restrict__ dst = (uint4*)(sWt + (PP ^ 1) * 12288);
    const int n16 = nbytes / 16;
    for (int i = tid; i < n16; i += 256)
      stage16(s4 + i, dst + (i & ~63));
  }

  // build B-frags from register-resident activations (VALU; overlaps staging)
  bf16x8 bf[2][SL > 0 ? SL : 1];
#pragma unroll
  for (int s = 0; s < SL; ++s) {
#pragma unroll
    for (int m = 0; m < 2; ++m) {
      uint2 p0 = pkv[m][2 * s], p1 = pkv[m][2 * s + 1];
      unsigned w0, w1, w2, w3;
      half_swap(p0.x, p1.x, q2, w0, w2);
      half_swap(p0.y, p1.y, q2, w1, w3);
      uint4 u = make_uint4(w0, w1, w2, w3);
      bf[m][s] = __builtin_bit_cast(bf16x8, u);
    }
  }

  const unsigned short* __restrict__ ldsbuf = sWt + PP * 12288;
  const uint4* __restrict__ wp = (const uint4*)wsrc;
#pragma unroll
  for (int t = 0; t < NT; ++t) {
    floatx16 acc[2];
#pragma unroll
    for (int i = 0; i < 16; ++i) { acc[0][i] = 0.0f; acc[1][i] = 0.0f; }
#pragma unroll
    for (int s = 0; s < S; ++s) {
      bf16x8 A;
      if (t < HT) {
        A = *(const bf16x8*)&ldsbuf[(t * S + s) * 512 + lane * 8];
      } else {
        uint4 a4 = wp[(t * S + s) * 64 + lane];
        A = __builtin_bit_cast(bf16x8, a4);
      }
      bf16x8 B0 = (s < SL) ? bf[0][s < SL ? s : 0] : tail[0][s - SL];
      bf16x8 B1 = (s < SL) ? bf[1][s < SL ? s : 0] : tail[1][s - SL];
      acc[0] = __builtin_amdgcn_mfma_f32_32x32x16_bf16(A, B0, acc[0], 0, 0, 0);
      acc[1] = __builtin_amdgcn_mfma_f32_32x32x16_bf16(A, B1, acc[1], 0, 0, 0);
    }
    if (OUTM == 2) {
      if (q2 == 0) {  // rgb = rows 0..2 -> regs 0..2 at q2==0
        float* o0 = out + (size_t)pt0 * 5;
        o0[0] = acc[0][0]; o0[1] = acc[0][1]; o0[2] = acc[0][2];
        float* o1 = out + (size_t)pt1 * 5;
        o1[0] = acc[1][0]; o1[1] = acc[1][1]; o1[2] = acc[1][2];
      }
    } else {
      if (OUTM == 0 || t < 4) {
#pragma unroll
        for (int m = 0; m < 2; ++m) {
#pragma unroll
          for (int gg = 0; gg < 4; ++gg) {
            float b0 = acc[m][4 * gg], b1 = acc[m][4 * gg + 1];
            float b2 = acc[m][4 * gg + 2], b3 = acc[m][4 * gg + 3];
            if (RELU) {
              b0 = fmaxf(b0, 0.f); b1 = fmaxf(b1, 0.f);
              b2 = fmaxf(b2, 0.f); b3 = fmaxf(b3, 0.f);
            }
            pkv[m][4 * t + gg] = make_uint2(pk2(b0, b1), pk2(b2, b3));
          }
        }
      }
      if (OUTM == 1 && q2 == 0) {
        if (t == 0) {  // density = feature[:,0] = row 0 (f32, pre-rounding)
          out[(size_t)pt0 * 5 + 3] = acc[0][0];
          out[(size_t)pt1 * 5 + 3] = acc[1][0];
        }
        if (t == 4) {  // blending = sigmoid(row 128)
          out[(size_t)pt0 * 5 + 4] = 1.0f / (1.0f + __expf(-acc[0][0]));
          out[(size_t)pt1 * 5 + 4] = 1.0f / (1.0f + __expf(-acc[1][0]));
        }
      }
    }
  }
}

__global__ __launch_bounds__(256, 2) void nerf_main(const float* __restrict__ x,
                                                    const unsigned short* __restrict__ ws,
                                                    float* __restrict__ out) {
  __shared__ __align__(16) unsigned short sWt[2 * 12288];  // 2 x 24 KB ping-pong LDS-half

  const int tid = (int)threadIdx.x;
  const int base = (int)blockIdx.x * 256;
  const int lane = tid & 63;
  const int w = tid >> 6;
  const int q2 = lane >> 5;
  const int l31 = lane & 31;
  const int pt0 = base + w * 64 + l31;

  // stage layer 0's LDS-half (tiles 0..1, 8 KB) into buf0 immediately
  {
    const uint4* s4 = (const uint4*)ws;
    uint4* dst = (uint4*)sWt;
#pragma unroll
    for (int i = 0; i < 2; ++i)
      stage16(s4 + i * 256 + tid, dst + ((i * 256 + tid) & ~63));
  }

  // per-lane x in registers (pt fixed per lane for whole kernel)
  float x0[6], x1[6];
  {
    const float* a = x + (size_t)pt0 * 6;
    const float* b = x + (size_t)(pt0 + 32) * 6;
#pragma unroll
    for (int c = 0; c < 3; ++c) {
      float2 u = *(const float2*)(a + 2 * c);
      float2 v = *(const float2*)(b + 2 * c);
      x0[2 * c] = u.x; x0[2 * c + 1] = u.y;
      x1[2 * c] = v.x; x1[2 * c + 1] = v.y;
    }
  }

  // positional trig frags computed ONCE (used by d1_0 and d2_0); overlaps staging
  bf16x8 pkt[2][4];
#pragma unroll
  for (int sl = 0; sl < 4; ++sl) {
    pkt[0][sl] = trig_frag<0>(x0, q2, sl);
    pkt[1][sl] = trig_frag<0>(x1, q2, sl);
  }

  uint2 pkv[2][16];

  //          S   SL NT HT PP relu  out         wsrc          next_src      next_stage_bytes
  run_layer< 4, 0, 4, 2, 0, true , 0>(ws + 0u,      ws + 8192u,   16384, sWt, pkv, pkt, out, base, tid); // d1_0
  run_layer< 8, 8, 4, 2, 1, true , 0>(ws + 8192u,   ws + 24576u,  16384, sWt, pkv, pkt, out, base, tid); // d1_1
  run_layer< 8, 8, 4, 2, 0, false, 0>(ws + 24576u,  ws + 40960u,  24576, sWt, pkv, pkt, out, base, tid); // d1_2 -> part1
  run_layer<12, 8, 4, 2, 1, true , 0>(ws + 40960u,  ws + 65536u,  16384, sWt, pkv, pkt, out, base, tid); // d2_0 [part1|enc_pos]
  run_layer< 8, 8, 4, 2, 0, true , 0>(ws + 65536u,  ws + 81920u,  16384, sWt, pkv, pkt, out, base, tid); // d2_1
  run_layer< 8, 8, 4, 2, 1, true , 0>(ws + 81920u,  ws + 98304u,  24576, sWt, pkv, pkt, out, base, tid); // d2_2
  run_layer< 8, 8, 5, 3, 0, false, 1>(ws + 98304u,  ws + 118784u, 20480, sWt, pkv, pkt, out, base, tid); // d2_3

  // view trig frags (pkt regs dead after d2_0 -> reuse pressure window)
  bf16x8 vw[2][4];
#pragma unroll
  for (int sl = 0; sl < 2; ++sl) {
    vw[0][sl] = trig_frag<1>(x0, q2, sl);
    vw[1][sl] = trig_frag<1>(x1, q2, sl);
  }
  vw[0][2] = vw[0][0]; vw[0][3] = vw[0][0];  // unused, keep defined
  vw[1][2] = vw[1][0]; vw[1][3] = vw[1][0];

  run_layer<10, 8, 4, 2, 1, true , 0>(ws + 118784u, ws + 139264u,  8192, sWt, pkv, vw,  out, base, tid); // c_0 [feature|enc_view]
  run_layer< 8, 8, 1, 1, 0, false, 2>(ws + 139264u, (const unsigned short*)nullptr, 0, sWt, pkv, pkt, out, base, tid); // c_1 -> rgb
}

extern "C" void kernel_launch(void* const* d_in, const int* in_sizes, int n_in,
                              void* d_out, int out_size, void* d_ws, size_t ws_size,
                              hipStream_t stream) {
  (void)n_in; (void)out_size; (void)ws_size;
  const float* x = (const float*)d_in[0];
  SrcPtrs sp;
  for (int i = 0; i < 9; ++i) sp.p[i] = (const float*)d_in[1 + i];
  unsigned short* ws = (unsigned short*)d_ws;
  float* out = (float*)d_out;
  const int N = in_sizes[0] / 6;

  prep_zero<<<70, 256, 0, stream>>>(ws);
  prep_fill<<<144, 256, 0, stream>>>(sp, ws);
  nerf_main<<<N / 256, 256, 0, stream>>>(x, ws, out);
}